// Round 7
// baseline (443.118 us; speedup 1.0000x reference)
//
#include <hip/hip_runtime.h>
#include <math.h>

#define BB 8
#define TT 4096
#define DDIM 512
#define KK 4096
#define NN (BB*TT)
#define EPS 0.035f

typedef __attribute__((ext_vector_type(8))) short bf16x8;
typedef __attribute__((ext_vector_type(4))) float f32x4;

__device__ __forceinline__ void async16(void* lds, const void* g) {
  __builtin_amdgcn_global_load_lds((const __attribute__((address_space(1))) void*)g,
                                   (__attribute__((address_space(3))) void*)lds, 16, 0, 0);
}

__device__ __forceinline__ unsigned pk_bf16(float a, float b) {
  unsigned ua = __float_as_uint(a); ua += 0x7FFFu + ((ua >> 16) & 1u);
  unsigned ub = __float_as_uint(b); ub += 0x7FFFu + ((ub >> 16) & 1u);
  return (ua >> 16) | (ub & 0xFFFF0000u);
}

__device__ __forceinline__ unsigned mono(float s) {
  unsigned u = __float_as_uint(s);
  return (u >> 31) ? ~u : (u | 0x80000000u);
}

// ---------- fused prep: bf16 convert + row stats for BOTH inputs ----------
__global__ __launch_bounds__(256) void prep_kernel(const float* __restrict__ x,
                                                   const float* __restrict__ embed,
                                                   short* __restrict__ xb,
                                                   short* __restrict__ eb,
                                                   float* __restrict__ inv2,
                                                   float* __restrict__ esq) {
  const float* src; short* dst; float* outv; int r; int mode;
  if (blockIdx.x < KK / 4) {
    src = embed; dst = eb; outv = esq; mode = 0;
    r = blockIdx.x * 4 + (threadIdx.x >> 6);
  } else {
    src = x; dst = xb; outv = inv2; mode = 1;
    r = (blockIdx.x - KK / 4) * 4 + (threadIdx.x >> 6);
  }
  int lane = threadIdx.x & 63;
  const float4* row4 = (const float4*)(src + (size_t)r * DDIM);
  float4 v0 = row4[lane];
  float4 v1 = row4[lane + 64];
  uint2 p0, p1;
  p0.x = pk_bf16(v0.x, v0.y); p0.y = pk_bf16(v0.z, v0.w);
  p1.x = pk_bf16(v1.x, v1.y); p1.y = pk_bf16(v1.z, v1.w);
  *(uint2*)(dst + (size_t)r * DDIM + lane * 4) = p0;
  *(uint2*)(dst + (size_t)r * DDIM + 256 + lane * 4) = p1;
  float ss = v0.x*v0.x + v0.y*v0.y + v0.z*v0.z + v0.w*v0.w
           + v1.x*v1.x + v1.y*v1.y + v1.z*v1.z + v1.w*v1.w;
  #pragma unroll
  for (int off = 32; off; off >>= 1) ss += __shfl_down(ss, off);
  if (lane == 0) outv[r] = mode ? 2.0f / fmaxf(sqrtf(ss), 1e-12f) : ss;
}

// ---------- main MFMA pass: EXACT round-2 structure (187us proven), (256,2) ----------
// grid 1024: bid&255 = m-block (128 rows), bid>>8 = k-quarter (1024 codes)
// single end-of-kernel top-2 reduction -> per-quarter plane
__global__ __launch_bounds__(256, 2) void vq_mfma(const short* __restrict__ xb,
                                                  const short* __restrict__ eb,
                                                  const float* __restrict__ esq,
                                                  const float* __restrict__ inv2,
                                                  float4* __restrict__ top2) {
  __shared__ short As[128 * 64];
  __shared__ short Bs[128 * 64];
  __shared__ float rS1[2][128];
  __shared__ float rS2[2][128];
  __shared__ int   rI1[2][128];

  const int tid = threadIdx.x;
  const int lane = tid & 63;
  const int w = tid >> 6;
  const int wr = w >> 1, wc = w & 1;
  const int q = lane >> 4, c16 = lane & 15;

  const int mb = blockIdx.x & 255;
  const int kq = blockIdx.x >> 8;
  const int n0 = mb * 128;
  const int kbase = kq * 1024;

  const int srow = w * 32 + (lane >> 3);
  const int scol = ((lane & 7) ^ (lane >> 3)) * 8;   // XOR swizzle: conflict-free frags
  const short* gA = xb + (size_t)(n0 + srow) * DDIM + scol;

  float s1[16], s2v[16];
  int   i1[16];
  #pragma unroll
  for (int s = 0; s < 16; ++s) { s1[s] = -3e38f; s2v[s] = -3e38f; i1[s] = 0; }

  f32x4 inv4[4];
  #pragma unroll
  for (int ti = 0; ti < 4; ++ti)
    inv4[ti] = *(const f32x4*)&inv2[n0 + wr * 64 + ti * 16 + q * 4];

  for (int c = 0; c < 8; ++c) {
    const int k0c = kbase + c * 128;
    const short* gB = eb + (size_t)(k0c + srow) * DDIM + scol;
    f32x4 acc[4][4];
    #pragma unroll
    for (int ti = 0; ti < 4; ++ti)
      #pragma unroll
      for (int tj = 0; tj < 4; ++tj) acc[ti][tj] = (f32x4){0.f, 0.f, 0.f, 0.f};

    for (int d0 = 0; d0 < DDIM; d0 += 64) {
      #pragma unroll
      for (int i = 0; i < 4; ++i) {
        async16(As + (w * 32 + i * 8) * 64, gA + (size_t)i * 8 * DDIM + d0);
        async16(Bs + (w * 32 + i * 8) * 64, gB + (size_t)i * 8 * DDIM + d0);
      }
      __syncthreads();
      #pragma unroll
      for (int ks = 0; ks < 2; ++ks) {
        const int ko = (((ks << 2) | q) ^ (lane & 7)) << 3;
        bf16x8 af[4], bf[4];
        #pragma unroll
        for (int ti = 0; ti < 4; ++ti)
          af[ti] = *(const bf16x8*)&As[(wr * 64 + ti * 16 + c16) * 64 + ko];
        #pragma unroll
        for (int tj = 0; tj < 4; ++tj)
          bf[tj] = *(const bf16x8*)&Bs[(wc * 64 + tj * 16 + c16) * 64 + ko];
        #pragma unroll
        for (int ti = 0; ti < 4; ++ti)
          #pragma unroll
          for (int tj = 0; tj < 4; ++tj)
            acc[ti][tj] = __builtin_amdgcn_mfma_f32_16x16x32_bf16(af[ti], bf[tj], acc[ti][tj], 0, 0, 0);
      }
      __syncthreads();
    }
    // epilogue: score = acc*inv2 - esq, update per-row top-2 (registers only)
    #pragma unroll
    for (int tj = 0; tj < 4; ++tj) {
      const int col = k0c + wc * 64 + tj * 16 + c16;
      const float nes = -esq[col];
      #pragma unroll
      for (int ti = 0; ti < 4; ++ti)
        #pragma unroll
        for (int r = 0; r < 4; ++r) {
          int slot = ti * 4 + r;
          float sc = fmaf(acc[ti][tj][r], inv4[ti][r], nes);
          float mn = fminf(sc, s1[slot]);
          s2v[slot] = fmaxf(s2v[slot], mn);
          if (sc > s1[slot]) { s1[slot] = sc; i1[slot] = col; }
        }
    }
  }

  // single reduction across the 16 lanes sharing each row
  #pragma unroll
  for (int slot = 0; slot < 16; ++slot) {
    float a1 = s1[slot], a2 = s2v[slot]; int ai = i1[slot];
    #pragma unroll
    for (int off = 1; off < 16; off <<= 1) {
      float b1 = __shfl_xor(a1, off);
      float b2 = __shfl_xor(a2, off);
      int   bi = __shfl_xor(ai, off);
      float ns2 = fmaxf(fmaxf(a2, b2), fminf(a1, b1));
      if (b1 > a1 || (b1 == a1 && bi < ai)) { a1 = b1; ai = bi; }
      a2 = ns2;
    }
    if (c16 == 0) {
      int row = wr * 64 + (slot >> 2) * 16 + q * 4 + (slot & 3);
      rS1[wc][row] = a1; rS2[wc][row] = a2; rI1[wc][row] = ai;
    }
  }
  __syncthreads();
  if (tid < 128) {
    float a1 = rS1[0][tid], a2 = rS2[0][tid]; int ai = rI1[0][tid];
    float b1 = rS1[1][tid], b2 = rS2[1][tid]; int bi = rI1[1][tid];
    float ns2 = fmaxf(fmaxf(a2, b2), fminf(a1, b1));
    if (b1 > a1 || (b1 == a1 && bi < ai)) { a1 = b1; ai = bi; }
    top2[(size_t)kq * NN + n0 + tid] = make_float4(a1, __int_as_float(ai), ns2, 0.f);
  }
}

// ---------- tail: merge quarter tops -> bounded candidate/event rescore -> gather ----------
// grid 512, 64 rows per block
__global__ __launch_bounds__(256) void tail_kernel(const float* __restrict__ x,
                                                   const float* __restrict__ embed,
                                                   const float* __restrict__ esq,
                                                   const float* __restrict__ inv2,
                                                   const float4* __restrict__ top2,
                                                   float* __restrict__ out_ind,
                                                   float* __restrict__ out_q) {
  __shared__ float4 qt[4][64];
  __shared__ int lidx[64];
  __shared__ unsigned long long pw[64];
  __shared__ int clist[512];          // (row<<12)|code  -- <=4 per row, hard bound
  __shared__ int elist[256];          // (row<<2)|quarter -- <=4 per row, hard bound
  __shared__ int ccnt, ecnt;
  __shared__ float trans[64 * 65];

  const int tid = threadIdx.x;
  const int lane = tid & 63, wv = tid >> 6;
  const int n0 = blockIdx.x * 64;

  // P1: stage quarter-top planes (coalesced: one wave per quarter)
  qt[wv][lane] = top2[(size_t)wv * NN + n0 + lane];
  if (tid == 0) { ccnt = 0; ecnt = 0; }
  __syncthreads();

  // P2: per-row merge + bounded candidate/event generation
  if (tid < 64) {
    float4 t[4];
    #pragma unroll
    for (int k = 0; k < 4; ++k) t[k] = qt[k][tid];
    float a1 = -3e38f; int ai = 0x7FFFFFFF;
    #pragma unroll
    for (int k = 0; k < 4; ++k) {
      int bi = __float_as_int(t[k].y);
      if (t[k].x > a1 || (t[k].x == a1 && bi < ai)) { a1 = t[k].x; ai = bi; }
    }
    const float thr = a1 - EPS;
    int amb = 0;
    #pragma unroll
    for (int k = 0; k < 4; ++k) {
      if (t[k].z >= thr) {                       // hidden-code risk: rescan quarter
        amb = 1;
        int p = atomicAdd(&ecnt, 1);
        elist[p] = (tid << 2) | k;
      } else if (t[k].x >= thr && __float_as_int(t[k].y) != ai) {
        amb = 1;
        int p = atomicAdd(&ccnt, 1);
        clist[p] = (tid << 12) | __float_as_int(t[k].y);
      }
    }
    if (amb) {
      lidx[tid] = -1; pw[tid] = 0ull;
      int p = atomicAdd(&ccnt, 1);
      clist[p] = (tid << 12) | ai;               // include bf16 top1 itself
    } else {
      lidx[tid] = ai;
    }
  }
  __syncthreads();

  // P3a: known-idx candidates — wave per candidate, exact fp32 dot
  {
    int e = ccnt;
    for (int i = wv; i < e; i += 4) {
      int ent = clist[i];
      int r = ent >> 12, code = ent & 4095;
      int grow = n0 + r;
      const float4* xp = (const float4*)&x[(size_t)grow * DDIM + lane * 8];
      const float4* ep = (const float4*)&embed[(size_t)code * DDIM + lane * 8];
      float4 xa = xp[0], xb4 = xp[1], ea = ep[0], eb4 = ep[1];
      float d = xa.x*ea.x + xa.y*ea.y + xa.z*ea.z + xa.w*ea.w
              + xb4.x*eb4.x + xb4.y*eb4.y + xb4.z*eb4.z + xb4.w*eb4.w;
      #pragma unroll
      for (int off = 1; off < 64; off <<= 1) d += __shfl_xor(d, off);
      if (lane == 0) {
        float sc = fmaf(d, inv2[grow], -esq[code]);
        unsigned long long pk = ((unsigned long long)mono(sc) << 32) | (unsigned)(~code);
        atomicMax(&pw[r], pk);
      }
    }
  }
  // P3b: events — wave per (row,quarter), full 1024-code exact rescan
  {
    int e = ecnt;
    for (int i = wv; i < e; i += 4) {
      int ent = elist[i];
      int r = ent >> 2, qtr = ent & 3;
      int grow = n0 + r;
      const float iv = inv2[grow];
      const float4* xp = (const float4*)&x[(size_t)grow * DDIM];
      float bs = -3e38f; int bi = 0x7FFFFFFF;
      for (int j = 0; j < 16; ++j) {
        int code = qtr * 1024 + j * 64 + lane;
        const float4* ep = (const float4*)&embed[(size_t)code * DDIM];
        float d = 0.f;
        #pragma unroll 8
        for (int d4 = 0; d4 < 128; ++d4) {
          float4 e4 = ep[d4];
          float4 x4 = xp[d4];          // broadcast across lanes (L1-hot)
          d += e4.x*x4.x + e4.y*x4.y + e4.z*x4.z + e4.w*x4.w;
        }
        float sc = fmaf(d, iv, -esq[code]);
        if (sc > bs || (sc == bs && code < bi)) { bs = sc; bi = code; }
      }
      unsigned long long pk = ((unsigned long long)mono(bs) << 32) | (unsigned)(~bi);
      #pragma unroll
      for (int off = 1; off < 64; off <<= 1) {
        unsigned long long p2 = __shfl_xor((long long)pk, off);
        if (p2 > pk) pk = p2;
      }
      if (lane == 0) atomicMax(&pw[r], pk);
    }
  }
  __syncthreads();

  // P4: resolve indices, write out_ind
  if (tid < 64) {
    int idx = lidx[tid];
    if (idx < 0) idx = (int)((~(unsigned)(pw[tid] & 0xFFFFFFFFull)) & 4095u);
    lidx[tid] = idx;
    out_ind[n0 + tid] = (float)idx;
  }
  __syncthreads();

  // P5: gather + transpose (proven pattern)
  const int bb = n0 >> 12;
  const int t0 = n0 & (TT - 1);
  for (int d0 = 0; d0 < DDIM; d0 += 64) {
    if (d0) __syncthreads();
    #pragma unroll
    for (int qq = 0; qq < 16; ++qq) {
      int tt2 = wv * 16 + qq;
      int e = lidx[tt2];
      trans[lane * 65 + tt2] = embed[(size_t)e * DDIM + d0 + lane];
    }
    __syncthreads();
    #pragma unroll
    for (int qq = 0; qq < 4; ++qq) {
      int dl = (tid >> 4) * 4 + qq;
      int t4 = (tid & 15) * 4;
      float4 o;
      o.x = trans[dl * 65 + t4 + 0];
      o.y = trans[dl * 65 + t4 + 1];
      o.z = trans[dl * 65 + t4 + 2];
      o.w = trans[dl * 65 + t4 + 3];
      *(float4*)&out_q[((size_t)bb * DDIM + d0 + dl) * TT + t0 + t4] = o;
    }
  }
}

extern "C" void kernel_launch(void* const* d_in, const int* in_sizes, int n_in,
                              void* d_out, int out_size, void* d_ws, size_t ws_size,
                              hipStream_t stream) {
  const float* x     = (const float*)d_in[0];
  const float* embed = (const float*)d_in[1];
  char* ws = (char*)d_ws;
  short* xb    = (short*)(ws);                 // 33,554,432 B
  short* eb    = (short*)(ws + 33554432);      //  4,194,304 B
  float* esq   = (float*)(ws + 37748736);      //     16,384 B
  float* inv2  = (float*)(ws + 37765120);      //    131,072 B
  float4* top2 = (float4*)(ws + 37896192);     //  2,097,152 B  (total ~40 MB)

  float* out_ind = (float*)d_out;
  float* out_q   = out_ind + NN;

  prep_kernel<<<KK / 4 + NN / 4, 256, 0, stream>>>(x, embed, xb, eb, inv2, esq);
  vq_mfma<<<1024, 256, 0, stream>>>(xb, eb, esq, inv2, top2);
  tail_kernel<<<NN / 64, 256, 0, stream>>>(x, embed, esq, inv2, top2, out_ind, out_q);
}